// Round 4
// baseline (898.564 us; speedup 1.0000x reference)
//
#include <hip/hip_runtime.h>

#define DD 128
#define SS 64
#define GG 256
#define LTDA 264  // abuf row stride (bf16 elems)
#define LTDS 72   // k1 subbuf row stride

typedef short short8 __attribute__((ext_vector_type(8)));
typedef float f32x4 __attribute__((ext_vector_type(4)));

// ---------- helpers ----------
__device__ __forceinline__ unsigned short f2bf(float x) {  // RNE
  unsigned u = __float_as_uint(x);
  u += 0x7FFFu + ((u >> 16) & 1u);
  return (unsigned short)(u >> 16);
}
__device__ __forceinline__ float bf2f(unsigned short b) {
  return __uint_as_float(((unsigned)b) << 16);
}
// pack 2 f32 -> bf16 pair (lo in low 16), RNE, 1 VALU instr
__device__ __forceinline__ unsigned pkbf(float lo, float hi) {
  unsigned r;
  asm("v_cvt_pk_bf16_f32 %0, %1, %2" : "=v"(r) : "v"(lo), "v"(hi));
  return r;
}
// fast sigmoid: ~4 VALU instrs (v_exp_f32 + v_rcp_f32)
__device__ __forceinline__ float fsig(float x) {
  return __builtin_amdgcn_rcpf(1.f + __expf(-x));
}

// Stage one 8KB weight-chunk image (global, pre-swizzled) into LDS.
__device__ __forceinline__ void stage8k(const unsigned short* __restrict__ g,
                                        unsigned short* l, int tid) {
  int wave = tid >> 6;
  const unsigned* gp = (const unsigned*)g;
  unsigned* lp = (unsigned*)l;
  __builtin_amdgcn_global_load_lds(
      (const __attribute__((address_space(1))) unsigned*)(gp + tid * 4),
      (__attribute__((address_space(3))) unsigned*)(lp + wave * 256), 16, 0, 0);
  __builtin_amdgcn_global_load_lds(
      (const __attribute__((address_space(1))) unsigned*)(gp + 1024 + tid * 4),
      (__attribute__((address_space(3))) unsigned*)(lp + 1024 + wave * 256), 16, 0, 0);
}

// ---- old-orientation micro (k1): A=data rows, B=weights. C: col=lane&15. ----
__device__ __forceinline__ void mfma8(const unsigned short* __restrict__ Abase,
                                      int astride,
                                      const unsigned short* __restrict__ wst,
                                      int k0, int m16, int quad, int mts,
                                      int nts, f32x4 acc[2][4]) {
  short8 af[2];
  af[0] = *(const short8*)(Abase + (size_t)((mts + 0) * 16 + m16) * astride + k0 + quad * 8);
  af[1] = *(const short8*)(Abase + (size_t)((mts + 1) * 16 + m16) * astride + k0 + quad * 8);
  short8 bf[4];
#pragma unroll
  for (int ni = 0; ni < 4; ++ni) {
    int n = (nts + ni) * 16 + m16;
    int s = (quad + (n >> 1)) & 3;
    bf[ni] = *(const short8*)(wst + n * 32 + s * 8);
  }
#pragma unroll
  for (int mi = 0; mi < 2; ++mi)
#pragma unroll
    for (int ni = 0; ni < 4; ++ni)
      acc[mi][ni] = __builtin_amdgcn_mfma_f32_16x16x32_bf16(af[mi], bf[ni],
                                                            acc[mi][ni], 0, 0, 0);
}

// ---- transposed micro (k3): A=weights (4 ch-tiles), B=data (2 row-tiles). ----
// C^T: lane holds D[ch=(mts+mi)*16+quad*4+r][row=(nts+ni)*16+m16].
__device__ __forceinline__ void mfma8t(const unsigned short* __restrict__ wst,
                                       const unsigned short* __restrict__ Abase,
                                       int k0, int m16, int quad, int mts,
                                       int nts, f32x4 acc[4][2]) {
  short8 wfr[4];
#pragma unroll
  for (int mi = 0; mi < 4; ++mi) {
    int ch = (mts + mi) * 16 + m16;
    int s = (quad + (ch >> 1)) & 3;
    wfr[mi] = *(const short8*)(wst + ch * 32 + s * 8);
  }
  short8 xf[2];
#pragma unroll
  for (int ni = 0; ni < 2; ++ni) {
    int row = (nts + ni) * 16 + m16;
    xf[ni] = *(const short8*)(Abase + (size_t)row * LTDA + k0 + quad * 8);
  }
#pragma unroll
  for (int mi = 0; mi < 4; ++mi)
#pragma unroll
    for (int ni = 0; ni < 2; ++ni)
      acc[mi][ni] = __builtin_amdgcn_mfma_f32_16x16x32_bf16(wfr[mi], xf[ni],
                                                            acc[mi][ni], 0, 0, 0);
}

// ---------- W_prep: bf16 transpose+swizzle of W1/Wg/Ws1 into chunk images ----
__global__ void w_prep(const float* __restrict__ W1, const float* __restrict__ Wg,
                       const float* __restrict__ Ws1, unsigned short* __restrict__ w1t,
                       unsigned short* __restrict__ wgt, unsigned short* __restrict__ ws1t) {
  int cb = blockIdx.x;  // 0..17
  const float* W;
  unsigned short* out;
  int kb;
  if (cb < 2) { W = W1; out = w1t; kb = cb; }
  else if (cb < 10) { W = Wg; out = wgt; kb = cb - 2; }
  else { W = Ws1; out = ws1t; kb = cb - 10; }
  out += (size_t)kb * 4096;
  int i = threadIdx.x;
#pragma unroll
  for (int t = 0; t < 2; ++t) {
    int u = i * 2 + t;              // 16B slot index, 0..511
    int n = u >> 2, s = u & 3;
    int kc = (s - (n >> 1)) & 3;
    int kbase = kb * 32 + kc * 8;
    unsigned short* o = out + u * 8;
#pragma unroll
    for (int j = 0; j < 8; ++j) o[j] = f2bf(W[(size_t)(kbase + j) * DD + n]);
  }
}

// ---------- K1_bn: bn1 stats via MFMA over sub@W1 ----------
__global__ __launch_bounds__(256, 6) void k1_bn(
    const float* __restrict__ sub, const unsigned short* __restrict__ w1t,
    const float* __restrict__ b1, float* __restrict__ bn1s,
    float* __restrict__ bn1q) {
  __shared__ unsigned short subbuf[64][LTDS];
  __shared__ unsigned short wstage[2][4096];
  __shared__ float bn1l[256];
  int tid = threadIdx.x;
  int row0 = blockIdx.x * 64;
  bn1l[tid] = 0.f;
  for (int i = tid; i < 1024; i += 256) {
    int r = i >> 4, c = (i & 15) * 4;
    float4 v = *(const float4*)&sub[(size_t)(row0 + r) * SS + c];
    uint2 uu;
    uu.x = pkbf(v.x, v.y);
    uu.y = pkbf(v.z, v.w);
    *(uint2*)&subbuf[r][c] = uu;
  }
  stage8k(w1t, &wstage[0][0], tid);
  stage8k(w1t + 4096, &wstage[1][0], tid);
  __syncthreads();
  int lane = tid & 63, wave = tid >> 6;
  int m16 = lane & 15, quad = lane >> 4;
  int mts = 2 * (wave & 1), nts = 4 * (wave >> 1);
  f32x4 acc[2][4];
#pragma unroll
  for (int mi = 0; mi < 2; ++mi)
#pragma unroll
    for (int ni = 0; ni < 4; ++ni) acc[mi][ni] = (f32x4){0.f, 0.f, 0.f, 0.f};
  mfma8(&subbuf[0][0], LTDS, &wstage[0][0], 0, m16, quad, mts, nts, acc);
  mfma8(&subbuf[0][0], LTDS, &wstage[1][0], 32, m16, quad, mts, nts, acc);
#pragma unroll
  for (int ni = 0; ni < 4; ++ni) {
    int col = (nts + ni) * 16 + m16;
    float b1c = b1[col];
    float s = 0.f, q = 0.f;
#pragma unroll
    for (int mi = 0; mi < 2; ++mi)
#pragma unroll
      for (int r = 0; r < 4; ++r) {
        float x = acc[mi][ni][r] + b1c;
        s += x;
        q += x * x;
      }
    s += __shfl_down(s, 32); s += __shfl_down(s, 16);
    q += __shfl_down(q, 32); q += __shfl_down(q, 16);
    if (lane < 16) {
      atomicAdd(&bn1l[col], s);
      atomicAdd(&bn1l[128 + col], q);
    }
  }
  __syncthreads();
  if (tid < 128) {
    atomicAdd(&bn1s[tid], bn1l[tid]);
    atomicAdd(&bn1q[tid], bn1l[128 + tid]);
  }
}

// ---------- K1_graph: per-graph sum/sumsq/count of h, 4-deep pipelined ------
__global__ __launch_bounds__(256, 8) void k1_graph(
    const float* __restrict__ h, const int* __restrict__ batch,
    float* __restrict__ gsum, float* __restrict__ gsq,
    float* __restrict__ counts, int N) {
  __shared__ int bc[256];
  int tid = threadIdx.x;
  int row0 = blockIdx.x * 256;
  {
    int row = row0 + tid;
    bc[tid] = (row < N) ? batch[row] : -1;
  }
  __syncthreads();
  int stripe = tid >> 5, c4 = (tid & 31) * 4;
  float sx = 0, sy = 0, sz = 0, sw = 0, qx = 0, qy = 0, qz = 0, qw = 0, cnt = 0;
  int gcur = -1;
  // 4-deep prefetch ring over rows stripe + 8*it, it = 0..31
  float4 vbuf[4];
  bool vval[4];
#pragma unroll
  for (int j = 0; j < 4; ++j) {
    int r = stripe + 8 * j;
    vval[j] = bc[r] >= 0;
    if (vval[j]) vbuf[j] = *(const float4*)&h[(size_t)(row0 + r) * DD + c4];
  }
#pragma unroll 1
  for (int mit = 0; mit < 8; ++mit) {
#pragma unroll
    for (int j = 0; j < 4; ++j) {
      int it = mit * 4 + j;
      int r = stripe + 8 * it;
      bool valid = vval[j];
      float4 v = vbuf[j];
      // issue load for row it+4 into this slot
      bool nv = (it + 4 < 32) && (bc[r + 32] >= 0);
      vval[j] = nv;
      if (nv) vbuf[j] = *(const float4*)&h[(size_t)(row0 + r + 32) * DD + c4];
      if (valid) {
        int g = bc[r];
        if (g != gcur) {
          if (gcur >= 0) {
            float* gp = &gsum[(size_t)gcur * DD + c4];
            float* qp = &gsq[(size_t)gcur * DD + c4];
            atomicAdd(gp + 0, sx); atomicAdd(gp + 1, sy);
            atomicAdd(gp + 2, sz); atomicAdd(gp + 3, sw);
            atomicAdd(qp + 0, qx); atomicAdd(qp + 1, qy);
            atomicAdd(qp + 2, qz); atomicAdd(qp + 3, qw);
            if ((tid & 31) == 0) atomicAdd(&counts[gcur], cnt);
          }
          gcur = g;
          sx = sy = sz = sw = qx = qy = qz = qw = cnt = 0.f;
        }
        sx += v.x; sy += v.y; sz += v.z; sw += v.w;
        qx = fmaf(v.x, v.x, qx); qy = fmaf(v.y, v.y, qy);
        qz = fmaf(v.z, v.z, qz); qw = fmaf(v.w, v.w, qw);
        cnt += 1.f;
      }
    }
  }
  if (gcur >= 0) {
    float* gp = &gsum[(size_t)gcur * DD + c4];
    float* qp = &gsq[(size_t)gcur * DD + c4];
    atomicAdd(gp + 0, sx); atomicAdd(gp + 1, sy);
    atomicAdd(gp + 2, sz); atomicAdd(gp + 3, sw);
    atomicAdd(qp + 0, qx); atomicAdd(qp + 1, qy);
    atomicAdd(qp + 2, qz); atomicAdd(qp + 3, qw);
    if ((tid & 31) == 0) atomicAdd(&counts[gcur], cnt);
  }
}

// ---------- tiny finalizers ----------
__global__ void k2a_bn_final(const float* __restrict__ s, const float* __restrict__ q,
                             const float* __restrict__ gamma, const float* __restrict__ beta,
                             float* __restrict__ sc, float* __restrict__ sh, float Nf) {
  int d = threadIdx.x;
  float m = s[d] / Nf;
  float v = q[d] / Nf - m * m;
  float r = rsqrtf(v + 1e-5f);
  float scv = gamma[d] * r;
  sc[d] = scv;
  sh[d] = beta[d] - m * scv;
}

__global__ void k2_fused(const float* __restrict__ bn1s, const float* __restrict__ bn1q,
                         const float* __restrict__ g1, const float* __restrict__ be1,
                         float* __restrict__ sc1, float* __restrict__ sh1, float Nf,
                         const float* __restrict__ gsum, const float* __restrict__ gsq,
                         const float* __restrict__ counts, float* __restrict__ gmean,
                         float* __restrict__ grstd) {
  int d = threadIdx.x;
  if (blockIdx.x == 0) {
    float m = bn1s[d] / Nf;
    float v = bn1q[d] / Nf - m * m;
    float r = rsqrtf(v + 1e-5f);
    float scv = g1[d] * r;
    sc1[d] = scv;
    sh1[d] = be1[d] - m * scv;
  } else {
    int g = blockIdx.x - 1;
    float c = counts[g];
    float cf = c > 1.f ? c : 1.f;
    size_t idx = (size_t)g * DD + d;
    float m = gsum[idx] / cf;
    float v = gsq[idx] / cf - m * m;
    float sd = sqrtf(fmaxf(v, 1e-8f));
    gmean[idx] = m;
    grstd[idx] = 1.f / (sd + 1e-8f);
  }
}

// ---------- K3: transposed MFMA chain; vectorized epilogues ----------
// 64-row blocks, 4 waves: wave covers 64 ch x 32 rows (acc[4][2]).
// LDS: abuf 33792 + wstage 16384 + bt 256 = 50432 -> 3 blocks/CU.
__global__ __launch_bounds__(256, 3) void k3_main(
    const float* __restrict__ h, const float* __restrict__ sub,
    const int* __restrict__ batch, const unsigned short* __restrict__ w1t,
    const unsigned short* __restrict__ wgt, const unsigned short* __restrict__ ws1t,
    const float* __restrict__ b1, const float* __restrict__ sc1,
    const float* __restrict__ sh1, const float* __restrict__ bg,
    const float* __restrict__ bs1, const float* __restrict__ gmean,
    const float* __restrict__ grstd, float* __restrict__ hfused,
    unsigned short* __restrict__ zp16, float* __restrict__ bn2s,
    float* __restrict__ bn2q, int N) {
  __shared__ unsigned short abuf[64][LTDA];   // cols 0..127: h->hf ; 128..255: sub->se->hd
  __shared__ unsigned short wstage[2][4096];
  __shared__ int bt[64];
  int tid = threadIdx.x;
  int row0 = blockIdx.x * 64;

  // stage h -> abuf[:,0:128] (bf16, b128 writes)
#pragma unroll
  for (int t = 0; t < 4; ++t) {
    int u = tid + t * 256;
    int r = u >> 4, c8 = (u & 15) * 8;
    const float* hp = &h[(size_t)(row0 + r) * DD + c8];
    float4 v0 = *(const float4*)hp, v1 = *(const float4*)(hp + 4);
    uint4 uu;
    uu.x = pkbf(v0.x, v0.y);
    uu.y = pkbf(v0.z, v0.w);
    uu.z = pkbf(v1.x, v1.y);
    uu.w = pkbf(v1.z, v1.w);
    *(uint4*)&abuf[r][c8] = uu;
  }
  // stage sub -> abuf[:,128:192]
#pragma unroll
  for (int t = 0; t < 2; ++t) {
    int u = tid + t * 256;
    int r = u >> 3, c8 = (u & 7) * 8;
    const float* sp = &sub[(size_t)(row0 + r) * SS + c8];
    float4 v0 = *(const float4*)sp, v1 = *(const float4*)(sp + 4);
    uint4 uu;
    uu.x = pkbf(v0.x, v0.y);
    uu.y = pkbf(v0.z, v0.w);
    uu.z = pkbf(v1.x, v1.y);
    uu.w = pkbf(v1.z, v1.w);
    *(uint4*)&abuf[r][128 + c8] = uu;
  }
  if (tid < 64) bt[tid] = batch[row0 + tid];
  stage8k(w1t, &wstage[0][0], tid);
  stage8k(w1t + 4096, &wstage[1][0], tid);
  __syncthreads();

  int lane = tid & 63, wave = tid >> 6;
  int m16 = lane & 15, quad = lane >> 4;
  int mts = 4 * (wave >> 1), nts = 2 * (wave & 1);
  f32x4 acc[4][2];

  // ---- Phase A: se^T = W1^T @ sub^T ----
#pragma unroll
  for (int mi = 0; mi < 4; ++mi)
#pragma unroll
    for (int ni = 0; ni < 2; ++ni) acc[mi][ni] = (f32x4){0.f, 0.f, 0.f, 0.f};
  mfma8t(&wstage[0][0], &abuf[0][0], 128, m16, quad, mts, nts, acc);
  mfma8t(&wstage[1][0], &abuf[0][0], 160, m16, quad, mts, nts, acc);
  __syncthreads();  // sub reads complete
  stage8k(wgt, &wstage[0][0], tid);
#pragma unroll
  for (int mi = 0; mi < 4; ++mi) {
    int ch0 = (mts + mi) * 16 + quad * 4;
    float4 b1v = *(const float4*)&b1[ch0];
    float4 s1v = *(const float4*)&sc1[ch0];
    float4 h1v = *(const float4*)&sh1[ch0];
#pragma unroll
    for (int ni = 0; ni < 2; ++ni) {
      int row = (nts + ni) * 16 + m16;
      float se0 = fmaxf(fmaf(acc[mi][ni][0] + b1v.x, s1v.x, h1v.x), 0.f);
      float se1 = fmaxf(fmaf(acc[mi][ni][1] + b1v.y, s1v.y, h1v.y), 0.f);
      float se2 = fmaxf(fmaf(acc[mi][ni][2] + b1v.z, s1v.z, h1v.z), 0.f);
      float se3 = fmaxf(fmaf(acc[mi][ni][3] + b1v.w, s1v.w, h1v.w), 0.f);
      uint2 uu;
      uu.x = pkbf(se0, se1);
      uu.y = pkbf(se2, se3);
      *(uint2*)&abuf[row][128 + ch0] = uu;
    }
  }
  __syncthreads();  // se visible; wgt chunk0 staged

  // ---- Phase B: gate^T = Wg^T @ [h|se]^T ----
#pragma unroll
  for (int mi = 0; mi < 4; ++mi)
#pragma unroll
    for (int ni = 0; ni < 2; ++ni) acc[mi][ni] = (f32x4){0.f, 0.f, 0.f, 0.f};
#pragma unroll 1
  for (int c = 0; c < 8; ++c) {
    if (c < 7) stage8k(wgt + (size_t)(c + 1) * 4096, &wstage[(c + 1) & 1][0], tid);
    mfma8t(&wstage[c & 1][0], &abuf[0][0], c * 32, m16, quad, mts, nts, acc);
    __syncthreads();
  }
  stage8k(ws1t, &wstage[0][0], tid);
  // epilogue B: owner-computes (same lane owns se cell read and hd cell write)
#pragma unroll
  for (int mi = 0; mi < 4; ++mi) {
    int ch0 = (mts + mi) * 16 + quad * 4;
    float4 bgv = *(const float4*)&bg[ch0];
#pragma unroll
    for (int ni = 0; ni < 2; ++ni) {
      int row = (nts + ni) * 16 + m16;
      int grow = row0 + row;
      float4 hv = *(const float4*)&h[(size_t)grow * DD + ch0];
      uint2 seu = *(const uint2*)&abuf[row][128 + ch0];
      int g = bt[row];
      float4 gm = *(const float4*)&gmean[(size_t)g * DD + ch0];
      float4 gr = *(const float4*)&grstd[(size_t)g * DD + ch0];
      float g0 = fsig(acc[mi][ni][0] + bgv.x);
      float g1v = fsig(acc[mi][ni][1] + bgv.y);
      float g2 = fsig(acc[mi][ni][2] + bgv.z);
      float g3 = fsig(acc[mi][ni][3] + bgv.w);
      float hf0 = fmaf(g0, bf2f((unsigned short)(seu.x & 0xffff)), hv.x);
      float hf1 = fmaf(g1v, bf2f((unsigned short)(seu.x >> 16)), hv.y);
      float hf2 = fmaf(g2, bf2f((unsigned short)(seu.y & 0xffff)), hv.z);
      float hf3 = fmaf(g3, bf2f((unsigned short)(seu.y >> 16)), hv.w);
      float hd0 = (hv.x - gm.x) * gr.x;
      float hd1 = (hv.y - gm.y) * gr.y;
      float hd2 = (hv.z - gm.z) * gr.z;
      float hd3 = (hv.w - gm.w) * gr.w;
      float4 hfv = {hf0, hf1, hf2, hf3};
      *(float4*)&hfused[(size_t)grow * DD + ch0] = hfv;
      uint2 uf, ud;
      uf.x = pkbf(hf0, hf1);
      uf.y = pkbf(hf2, hf3);
      ud.x = pkbf(hd0, hd1);
      ud.y = pkbf(hd2, hd3);
      *(uint2*)&abuf[row][ch0] = uf;
      *(uint2*)&abuf[row][128 + ch0] = ud;
    }
  }
  __syncthreads();  // hf/hd visible; ws1 chunk0 staged

  // ---- Phase C: z^T = Ws1^T @ [hf|hd]^T ----
#pragma unroll
  for (int mi = 0; mi < 4; ++mi)
#pragma unroll
    for (int ni = 0; ni < 2; ++ni) acc[mi][ni] = (f32x4){0.f, 0.f, 0.f, 0.f};
#pragma unroll 1
  for (int c = 0; c < 8; ++c) {
    if (c < 7) stage8k(ws1t + (size_t)(c + 1) * 4096, &wstage[(c + 1) & 1][0], tid);
    mfma8t(&wstage[c & 1][0], &abuf[0][0], c * 32, m16, quad, mts, nts, acc);
    __syncthreads();
  }
  // epilogue C: bf16 zpre stores + bn2 partial sums via scratch in dead abuf
  float* scr = (float*)&abuf[0][0];   // s: [32][132] ; q at +4224
  int srow = (wave & 1) * 16 + m16;   // 32 row-slots (nts-half x m16)
#pragma unroll
  for (int mi = 0; mi < 4; ++mi) {
    int ch0 = (mts + mi) * 16 + quad * 4;
    float4 bsv = *(const float4*)&bs1[ch0];
    f32x4 s4 = (f32x4){0.f, 0.f, 0.f, 0.f};
    f32x4 q4 = (f32x4){0.f, 0.f, 0.f, 0.f};
#pragma unroll
    for (int ni = 0; ni < 2; ++ni) {
      int grow = row0 + (nts + ni) * 16 + m16;
      float z0 = acc[mi][ni][0] + bsv.x;
      float z1 = acc[mi][ni][1] + bsv.y;
      float z2 = acc[mi][ni][2] + bsv.z;
      float z3 = acc[mi][ni][3] + bsv.w;
      uint2 uz;
      uz.x = pkbf(z0, z1);
      uz.y = pkbf(z2, z3);
      *(uint2*)&zp16[(size_t)grow * DD + ch0] = uz;
      s4[0] += z0; s4[1] += z1; s4[2] += z2; s4[3] += z3;
      q4[0] = fmaf(z0, z0, q4[0]); q4[1] = fmaf(z1, z1, q4[1]);
      q4[2] = fmaf(z2, z2, q4[2]); q4[3] = fmaf(z3, z3, q4[3]);
    }
    *(f32x4*)&scr[srow * 132 + ch0] = s4;
    *(f32x4*)&scr[4224 + srow * 132 + ch0] = q4;
  }
  __syncthreads();
  if (tid < 128) {
    float s = 0.f, q = 0.f;
#pragma unroll 4
    for (int i = 0; i < 32; ++i) {
      s += scr[i * 132 + tid];
      q += scr[4224 + i * 132 + tid];
    }
    atomicAdd(&bn2s[tid], s);
    atomicAdd(&bn2q[tid], q);
  }
}

// ---------- K56: logit -> e=exp(logit) -> accumulate denom & sum(hf*e) ------
// 4-deep pipelined row loop per 32-lane stripe.
__global__ __launch_bounds__(256, 6) void k56_score(
    const unsigned short* __restrict__ zp16, const float* __restrict__ hf,
    const int* __restrict__ batch, const float* __restrict__ sc2,
    const float* __restrict__ sh2, const float* __restrict__ Ws2,
    const float* __restrict__ bs2, float* __restrict__ denom,
    float* __restrict__ wf, int N) {
  __shared__ int bc[256];
  int tid = threadIdx.x;
  int row0 = blockIdx.x * 256;
  {
    int row = row0 + tid;
    bc[tid] = (row < N) ? batch[row] : -1;
  }
  __syncthreads();
  int stripe = tid >> 5, c4 = (tid & 31) * 4;
  float4 s2 = *(const float4*)&sc2[c4];
  float4 h2 = *(const float4*)&sh2[c4];
  float4 w2 = *(const float4*)&Ws2[c4];
  float b2 = bs2[0];
  float ax = 0, ay = 0, az = 0, aw = 0, ds = 0;
  int gcur = -1;
  uint2 vz[4];
  float4 vh[4];
  bool vval[4];
#pragma unroll
  for (int j = 0; j < 4; ++j) {
    int r = stripe + 8 * j;
    vval[j] = bc[r] >= 0;
    if (vval[j]) {
      vz[j] = *(const uint2*)&zp16[(size_t)(row0 + r) * DD + c4];
      vh[j] = *(const float4*)&hf[(size_t)(row0 + r) * DD + c4];
    }
  }
#pragma unroll 1
  for (int mit = 0; mit < 8; ++mit) {
#pragma unroll
    for (int j = 0; j < 4; ++j) {
      int it = mit * 4 + j;
      int r = stripe + 8 * it;
      bool valid = vval[j];
      uint2 z2v = vz[j];
      float4 hv = vh[j];
      bool nv = (it + 4 < 32) && (bc[r + 32] >= 0);
      vval[j] = nv;
      if (nv) {
        vz[j] = *(const uint2*)&zp16[(size_t)(row0 + r + 32) * DD + c4];
        vh[j] = *(const float4*)&hf[(size_t)(row0 + r + 32) * DD + c4];
      }
      if (valid) {
        int g = bc[r];
        if (g != gcur) {
          if (gcur >= 0) {
            float* wp = &wf[(size_t)gcur * DD + c4];
            atomicAdd(wp + 0, ax); atomicAdd(wp + 1, ay);
            atomicAdd(wp + 2, az); atomicAdd(wp + 3, aw);
            if ((tid & 31) == 0) atomicAdd(&denom[gcur], ds);
          }
          gcur = g;
          ax = ay = az = aw = ds = 0.f;
        }
        float z0 = bf2f((unsigned short)(z2v.x & 0xffff));
        float z1 = bf2f((unsigned short)(z2v.x >> 16));
        float zz2 = bf2f((unsigned short)(z2v.y & 0xffff));
        float z3 = bf2f((unsigned short)(z2v.y >> 16));
        float p = fmaxf(fmaf(z0, s2.x, h2.x), 0.f) * w2.x;
        p = fmaf(fmaxf(fmaf(z1, s2.y, h2.y), 0.f), w2.y, p);
        p = fmaf(fmaxf(fmaf(zz2, s2.z, h2.z), 0.f), w2.z, p);
        p = fmaf(fmaxf(fmaf(z3, s2.w, h2.w), 0.f), w2.w, p);
        p += __shfl_xor(p, 16); p += __shfl_xor(p, 8);
        p += __shfl_xor(p, 4);  p += __shfl_xor(p, 2);
        p += __shfl_xor(p, 1);
        float e = __expf(p + b2);
        ax = fmaf(hv.x, e, ax); ay = fmaf(hv.y, e, ay);
        az = fmaf(hv.z, e, az); aw = fmaf(hv.w, e, aw);
        ds += e;
      }
    }
  }
  if (gcur >= 0) {
    float* wp = &wf[(size_t)gcur * DD + c4];
    atomicAdd(wp + 0, ax); atomicAdd(wp + 1, ay);
    atomicAdd(wp + 2, az); atomicAdd(wp + 3, aw);
    if ((tid & 31) == 0) atomicAdd(&denom[gcur], ds);
  }
}

// ---------- K7: out = alpha*wf/denom + (1-alpha)*gmean ----------
__global__ void k7_out(const float* __restrict__ wf, const float* __restrict__ denom,
                       const float* __restrict__ gmean, const float* __restrict__ mix,
                       float* __restrict__ out) {
  int g = blockIdx.x, d = threadIdx.x;
  float alpha = 1.f / (1.f + expf(-mix[0]));
  float dn = denom[g];
  size_t idx = (size_t)g * DD + d;
  float w = (dn > 0.f) ? wf[idx] / dn : 0.f;
  out[idx] = alpha * w + (1.f - alpha) * gmean[idx];
}

extern "C" void kernel_launch(void* const* d_in, const int* in_sizes, int n_in,
                              void* d_out, int out_size, void* d_ws, size_t ws_size,
                              hipStream_t stream) {
  const float* h   = (const float*)d_in[0];
  const float* sub = (const float*)d_in[1];
  const int* batch = (const int*)d_in[2];
  const float* W1  = (const float*)d_in[3];
  const float* b1  = (const float*)d_in[4];
  const float* g1  = (const float*)d_in[5];
  const float* be1 = (const float*)d_in[6];
  const float* Wg  = (const float*)d_in[7];
  const float* bg  = (const float*)d_in[8];
  const float* Ws1 = (const float*)d_in[9];
  const float* bs1 = (const float*)d_in[10];
  const float* g2  = (const float*)d_in[11];
  const float* be2 = (const float*)d_in[12];
  const float* Ws2 = (const float*)d_in[13];
  const float* bs2 = (const float*)d_in[14];
  const float* mix = (const float*)d_in[15];
  float* out = (float*)d_out;
  const int N = in_sizes[0] / DD;  // 400000 (divisible by 64)
  const int nB1 = N / 64;          // 6250
  const int nBG = (N + 255) / 256; // 1563

  float* ws = (float*)d_ws;
  size_t off = 0;
  float* hf    = ws + off; off += (size_t)N * DD;
  unsigned short* zp16 = (unsigned short*)(ws + off); off += (size_t)N * DD / 2;
  float* zbase = ws + off;
  float* gsum  = ws + off; off += (size_t)GG * DD;
  float* gsq   = ws + off; off += (size_t)GG * DD;
  float* wf    = ws + off; off += (size_t)GG * DD;
  float* bn1s  = ws + off; off += 128;
  float* bn1q  = ws + off; off += 128;
  float* bn2s  = ws + off; off += 128;
  float* bn2q  = ws + off; off += 128;
  float* counts = ws + off; off += GG;
  float* denom  = ws + off; off += GG;
  size_t zcount = (size_t)(ws + off - zbase);
  float* gmean = ws + off; off += (size_t)GG * DD;
  float* grstd = ws + off; off += (size_t)GG * DD;
  float* sc1 = ws + off; off += 128;
  float* sh1 = ws + off; off += 128;
  float* sc2 = ws + off; off += 128;
  float* sh2 = ws + off; off += 128;
  // weight images: sizes in SHORTS; offsets advance in FLOAT units (shorts/2).
  unsigned short* w1t  = (unsigned short*)(ws + off); off += 8192 / 2;    // 2 chunks x 4096 shorts
  unsigned short* wgt  = (unsigned short*)(ws + off); off += 32768 / 2;   // 8 chunks x 4096 shorts
  unsigned short* ws1t = (unsigned short*)(ws + off); off += 32768 / 2;   // 8 chunks x 4096 shorts

  hipMemsetAsync(zbase, 0, zcount * sizeof(float), stream);
  w_prep<<<18, 256, 0, stream>>>(W1, Wg, Ws1, w1t, wgt, ws1t);

  k1_bn<<<nB1, 256, 0, stream>>>(sub, w1t, b1, bn1s, bn1q);
  k1_graph<<<nBG, 256, 0, stream>>>(h, batch, gsum, gsq, counts, N);
  k2_fused<<<1 + GG, 128, 0, stream>>>(bn1s, bn1q, g1, be1, sc1, sh1, (float)N,
                                       gsum, gsq, counts, gmean, grstd);

  k3_main<<<nB1, 256, 0, stream>>>(h, sub, batch, w1t, wgt, ws1t, b1, sc1, sh1,
                                   bg, bs1, gmean, grstd, hf, zp16, bn2s, bn2q, N);

  k2a_bn_final<<<1, 128, 0, stream>>>(bn2s, bn2q, g2, be2, sc2, sh2, (float)N);
  k56_score<<<nBG, 256, 0, stream>>>(zp16, hf, batch, sc2, sh2, Ws2, bs2,
                                     denom, wf, N);
  k7_out<<<GG, 128, 0, stream>>>(wf, denom, gmean, mix, out);
}

// Round 6
// 747.798 us; speedup vs baseline: 1.2016x; 1.2016x over previous
//
#include <hip/hip_runtime.h>

#define DD 128
#define SS 64
#define GG 256
#define NREP 64   // replicated BN accumulators (atomic-contention fix)
#define LTDA 264  // abuf row stride (bf16 elems)
#define LTDS 72   // k1 subbuf row stride

typedef short short8 __attribute__((ext_vector_type(8)));
typedef float f32x4 __attribute__((ext_vector_type(4)));

// ---------- helpers ----------
__device__ __forceinline__ unsigned short f2bf(float x) {  // RNE
  unsigned u = __float_as_uint(x);
  u += 0x7FFFu + ((u >> 16) & 1u);
  return (unsigned short)(u >> 16);
}
__device__ __forceinline__ float bf2f(unsigned short b) {
  return __uint_as_float(((unsigned)b) << 16);
}
// pack 2 f32 -> bf16 pair (lo in low 16), RNE, 1 VALU instr
__device__ __forceinline__ unsigned pkbf(float lo, float hi) {
  unsigned r;
  asm("v_cvt_pk_bf16_f32 %0, %1, %2" : "=v"(r) : "v"(lo), "v"(hi));
  return r;
}
// fast sigmoid: ~4 VALU instrs (v_exp_f32 + v_rcp_f32)
__device__ __forceinline__ float fsig(float x) {
  return __builtin_amdgcn_rcpf(1.f + __expf(-x));
}

// Stage one 8KB weight-chunk image (global, pre-swizzled) into LDS.
__device__ __forceinline__ void stage8k(const unsigned short* __restrict__ g,
                                        unsigned short* l, int tid) {
  int wave = tid >> 6;
  const unsigned* gp = (const unsigned*)g;
  unsigned* lp = (unsigned*)l;
  __builtin_amdgcn_global_load_lds(
      (const __attribute__((address_space(1))) unsigned*)(gp + tid * 4),
      (__attribute__((address_space(3))) unsigned*)(lp + wave * 256), 16, 0, 0);
  __builtin_amdgcn_global_load_lds(
      (const __attribute__((address_space(1))) unsigned*)(gp + 1024 + tid * 4),
      (__attribute__((address_space(3))) unsigned*)(lp + 1024 + wave * 256), 16, 0, 0);
}

// ---- old-orientation micro (k1): A=data rows, B=weights. C: col=lane&15. ----
__device__ __forceinline__ void mfma8(const unsigned short* __restrict__ Abase,
                                      int astride,
                                      const unsigned short* __restrict__ wst,
                                      int k0, int m16, int quad, int mts,
                                      int nts, f32x4 acc[2][4]) {
  short8 af[2];
  af[0] = *(const short8*)(Abase + (size_t)((mts + 0) * 16 + m16) * astride + k0 + quad * 8);
  af[1] = *(const short8*)(Abase + (size_t)((mts + 1) * 16 + m16) * astride + k0 + quad * 8);
  short8 bf[4];
#pragma unroll
  for (int ni = 0; ni < 4; ++ni) {
    int n = (nts + ni) * 16 + m16;
    int s = (quad + (n >> 1)) & 3;
    bf[ni] = *(const short8*)(wst + n * 32 + s * 8);
  }
#pragma unroll
  for (int mi = 0; mi < 2; ++mi)
#pragma unroll
    for (int ni = 0; ni < 4; ++ni)
      acc[mi][ni] = __builtin_amdgcn_mfma_f32_16x16x32_bf16(af[mi], bf[ni],
                                                            acc[mi][ni], 0, 0, 0);
}

// ---- transposed micro (k3): A=weights (4 ch-tiles), B=data (2 row-tiles). ----
// C^T: lane holds D[ch=(mts+mi)*16+quad*4+r][row=(nts+ni)*16+m16].
__device__ __forceinline__ void mfma8t(const unsigned short* __restrict__ wst,
                                       const unsigned short* __restrict__ Abase,
                                       int k0, int m16, int quad, int mts,
                                       int nts, f32x4 acc[4][2]) {
  short8 wfr[4];
#pragma unroll
  for (int mi = 0; mi < 4; ++mi) {
    int ch = (mts + mi) * 16 + m16;
    int s = (quad + (ch >> 1)) & 3;
    wfr[mi] = *(const short8*)(wst + ch * 32 + s * 8);
  }
  short8 xf[2];
#pragma unroll
  for (int ni = 0; ni < 2; ++ni) {
    int row = (nts + ni) * 16 + m16;
    xf[ni] = *(const short8*)(Abase + (size_t)row * LTDA + k0 + quad * 8);
  }
#pragma unroll
  for (int mi = 0; mi < 4; ++mi)
#pragma unroll
    for (int ni = 0; ni < 2; ++ni)
      acc[mi][ni] = __builtin_amdgcn_mfma_f32_16x16x32_bf16(wfr[mi], xf[ni],
                                                            acc[mi][ni], 0, 0, 0);
}

// ---------- W_prep: bf16 transpose+swizzle of W1/Wg/Ws1 into chunk images ----
__global__ void w_prep(const float* __restrict__ W1, const float* __restrict__ Wg,
                       const float* __restrict__ Ws1, unsigned short* __restrict__ w1t,
                       unsigned short* __restrict__ wgt, unsigned short* __restrict__ ws1t) {
  int cb = blockIdx.x;  // 0..17
  const float* W;
  unsigned short* out;
  int kb;
  if (cb < 2) { W = W1; out = w1t; kb = cb; }
  else if (cb < 10) { W = Wg; out = wgt; kb = cb - 2; }
  else { W = Ws1; out = ws1t; kb = cb - 10; }
  out += (size_t)kb * 4096;
  int i = threadIdx.x;
#pragma unroll
  for (int t = 0; t < 2; ++t) {
    int u = i * 2 + t;              // 16B slot index, 0..511
    int n = u >> 2, s = u & 3;
    int kc = (s - (n >> 1)) & 3;
    int kbase = kb * 32 + kc * 8;
    unsigned short* o = out + u * 8;
#pragma unroll
    for (int j = 0; j < 8; ++j) o[j] = f2bf(W[(size_t)(kbase + j) * DD + n]);
  }
}

// ---------- K1 fused: bn1 stats + graph stats, roles interleaved 1:4 --------
// Graph blocks at bid%5==0 (while available) so co-resident blocks mix roles.
// bn1 partial sums go to 64 replicated accumulators (contention fix).
__global__ __launch_bounds__(256, 4) void k1_fused(
    const float* __restrict__ sub, const unsigned short* __restrict__ w1t,
    const float* __restrict__ b1, float* __restrict__ bn1p,
    const float* __restrict__ h, const int* __restrict__ batch,
    float* __restrict__ gsum, float* __restrict__ gsq,
    float* __restrict__ counts, int N, int nBG) {
  __shared__ unsigned short subbuf[64][LTDS];
  __shared__ unsigned short wstage[2][4096];
  __shared__ float bn1l[256];
  int tid = threadIdx.x;
  int bid = blockIdx.x;
  int g5 = bid / 5, r5 = bid - g5 * 5;
  bool isGraph = (r5 == 0) && (g5 < nBG);

  if (isGraph) {
    // ---- graph-stats path (4-deep pipelined) ----
    int* bc = (int*)bn1l;
    int row0 = g5 * 256;
    {
      int row = row0 + tid;
      bc[tid] = (row < N) ? batch[row] : -1;
    }
    __syncthreads();
    int stripe = tid >> 5, c4 = (tid & 31) * 4;
    float sx = 0, sy = 0, sz = 0, sw = 0, qx = 0, qy = 0, qz = 0, qw = 0, cnt = 0;
    int gcur = -1;
    float4 vbuf[4];
    bool vval[4];
#pragma unroll
    for (int j = 0; j < 4; ++j) {
      int r = stripe + 8 * j;
      vval[j] = bc[r] >= 0;
      if (vval[j]) vbuf[j] = *(const float4*)&h[(size_t)(row0 + r) * DD + c4];
    }
#pragma unroll 1
    for (int mit = 0; mit < 8; ++mit) {
#pragma unroll
      for (int j = 0; j < 4; ++j) {
        int it = mit * 4 + j;
        int r = stripe + 8 * it;
        bool valid = vval[j];
        float4 v = vbuf[j];
        bool nv = (it + 4 < 32) && (bc[r + 32] >= 0);
        vval[j] = nv;
        if (nv) vbuf[j] = *(const float4*)&h[(size_t)(row0 + r + 32) * DD + c4];
        if (valid) {
          int g = bc[r];
          if (g != gcur) {
            if (gcur >= 0) {
              float* gp = &gsum[(size_t)gcur * DD + c4];
              float* qp = &gsq[(size_t)gcur * DD + c4];
              atomicAdd(gp + 0, sx); atomicAdd(gp + 1, sy);
              atomicAdd(gp + 2, sz); atomicAdd(gp + 3, sw);
              atomicAdd(qp + 0, qx); atomicAdd(qp + 1, qy);
              atomicAdd(qp + 2, qz); atomicAdd(qp + 3, qw);
              if ((tid & 31) == 0) atomicAdd(&counts[gcur], cnt);
            }
            gcur = g;
            sx = sy = sz = sw = qx = qy = qz = qw = cnt = 0.f;
          }
          sx += v.x; sy += v.y; sz += v.z; sw += v.w;
          qx = fmaf(v.x, v.x, qx); qy = fmaf(v.y, v.y, qy);
          qz = fmaf(v.z, v.z, qz); qw = fmaf(v.w, v.w, qw);
          cnt += 1.f;
        }
      }
    }
    if (gcur >= 0) {
      float* gp = &gsum[(size_t)gcur * DD + c4];
      float* qp = &gsq[(size_t)gcur * DD + c4];
      atomicAdd(gp + 0, sx); atomicAdd(gp + 1, sy);
      atomicAdd(gp + 2, sz); atomicAdd(gp + 3, sw);
      atomicAdd(qp + 0, qx); atomicAdd(qp + 1, qy);
      atomicAdd(qp + 2, qz); atomicAdd(qp + 3, qw);
      if ((tid & 31) == 0) atomicAdd(&counts[gcur], cnt);
    }
    return;
  }

  // ---- bn1-stats path ----
  int nbefore = (g5 + 1 < nBG) ? (g5 + 1) : nBG;
  int row0 = (bid - nbefore) * 64;
  bn1l[tid] = 0.f;
  for (int i = tid; i < 1024; i += 256) {
    int r = i >> 4, c = (i & 15) * 4;
    float4 v = *(const float4*)&sub[(size_t)(row0 + r) * SS + c];
    uint2 uu;
    uu.x = pkbf(v.x, v.y);
    uu.y = pkbf(v.z, v.w);
    *(uint2*)&subbuf[r][c] = uu;
  }
  stage8k(w1t, &wstage[0][0], tid);
  stage8k(w1t + 4096, &wstage[1][0], tid);
  __syncthreads();
  int lane = tid & 63, wave = tid >> 6;
  int m16 = lane & 15, quad = lane >> 4;
  int mts = 2 * (wave & 1), nts = 4 * (wave >> 1);
  f32x4 acc[2][4];
#pragma unroll
  for (int mi = 0; mi < 2; ++mi)
#pragma unroll
    for (int ni = 0; ni < 4; ++ni) acc[mi][ni] = (f32x4){0.f, 0.f, 0.f, 0.f};
  mfma8(&subbuf[0][0], LTDS, &wstage[0][0], 0, m16, quad, mts, nts, acc);
  mfma8(&subbuf[0][0], LTDS, &wstage[1][0], 32, m16, quad, mts, nts, acc);
#pragma unroll
  for (int ni = 0; ni < 4; ++ni) {
    int col = (nts + ni) * 16 + m16;
    float b1c = b1[col];
    float s = 0.f, q = 0.f;
#pragma unroll
    for (int mi = 0; mi < 2; ++mi)
#pragma unroll
      for (int r = 0; r < 4; ++r) {
        float x = acc[mi][ni][r] + b1c;
        s += x;
        q += x * x;
      }
    s += __shfl_down(s, 32); s += __shfl_down(s, 16);
    q += __shfl_down(q, 32); q += __shfl_down(q, 16);
    if (lane < 16) {
      atomicAdd(&bn1l[col], s);
      atomicAdd(&bn1l[128 + col], q);
    }
  }
  __syncthreads();
  // one atomic per thread into replica (bid & 63): contention ~98/address
  atomicAdd(&bn1p[(size_t)(bid & (NREP - 1)) * 256 + tid], bn1l[tid]);
}

// ---------- tiny finalizers ----------
__global__ void k2a_bn_final(const float* __restrict__ bn2p,
                             const float* __restrict__ gamma, const float* __restrict__ beta,
                             float* __restrict__ sc, float* __restrict__ sh, float Nf) {
  int d = threadIdx.x;
  float s = 0.f, q = 0.f;
#pragma unroll 4
  for (int r = 0; r < NREP; ++r) {
    s += bn2p[r * 256 + d];
    q += bn2p[r * 256 + 128 + d];
  }
  float m = s / Nf;
  float v = q / Nf - m * m;
  float rr = rsqrtf(v + 1e-5f);
  float scv = gamma[d] * rr;
  sc[d] = scv;
  sh[d] = beta[d] - m * scv;
}

__global__ void k2_fused(const float* __restrict__ bn1p,
                         const float* __restrict__ g1, const float* __restrict__ be1,
                         float* __restrict__ sc1, float* __restrict__ sh1, float Nf,
                         const float* __restrict__ gsum, const float* __restrict__ gsq,
                         const float* __restrict__ counts, float* __restrict__ gmean,
                         float* __restrict__ grstd) {
  int d = threadIdx.x;
  if (blockIdx.x == 0) {
    float s = 0.f, q = 0.f;
#pragma unroll 4
    for (int r = 0; r < NREP; ++r) {
      s += bn1p[r * 256 + d];
      q += bn1p[r * 256 + 128 + d];
    }
    float m = s / Nf;
    float v = q / Nf - m * m;
    float rr = rsqrtf(v + 1e-5f);
    float scv = g1[d] * rr;
    sc1[d] = scv;
    sh1[d] = be1[d] - m * scv;
  } else {
    int g = blockIdx.x - 1;
    float c = counts[g];
    float cf = c > 1.f ? c : 1.f;
    size_t idx = (size_t)g * DD + d;
    float m = gsum[idx] / cf;
    float v = gsq[idx] / cf - m * m;
    float sd = sqrtf(fmaxf(v, 1e-8f));
    gmean[idx] = m;
    grstd[idx] = 1.f / (sd + 1e-8f);
  }
}

// ---------- K3: transposed MFMA chain; vectorized epilogues ----------
// 64-row blocks, 4 waves: wave covers 64 ch x 32 rows (acc[4][2]).
// LDS: abuf 33792 + wstage 16384 + bt 256 = 50432 -> 3 blocks/CU.
__global__ __launch_bounds__(256, 3) void k3_main(
    const float* __restrict__ h, const float* __restrict__ sub,
    const int* __restrict__ batch, const unsigned short* __restrict__ w1t,
    const unsigned short* __restrict__ wgt, const unsigned short* __restrict__ ws1t,
    const float* __restrict__ b1, const float* __restrict__ sc1,
    const float* __restrict__ sh1, const float* __restrict__ bg,
    const float* __restrict__ bs1, const float* __restrict__ gmean,
    const float* __restrict__ grstd, float* __restrict__ hfused,
    unsigned short* __restrict__ zp16, float* __restrict__ bn2p, int N) {
  __shared__ unsigned short abuf[64][LTDA];   // cols 0..127: h->hf ; 128..255: sub->se->hd
  __shared__ unsigned short wstage[2][4096];
  __shared__ int bt[64];
  int tid = threadIdx.x;
  int row0 = blockIdx.x * 64;

  // stage h -> abuf[:,0:128] (bf16, b128 writes)
#pragma unroll
  for (int t = 0; t < 4; ++t) {
    int u = tid + t * 256;
    int r = u >> 4, c8 = (u & 15) * 8;
    const float* hp = &h[(size_t)(row0 + r) * DD + c8];
    float4 v0 = *(const float4*)hp, v1 = *(const float4*)(hp + 4);
    uint4 uu;
    uu.x = pkbf(v0.x, v0.y);
    uu.y = pkbf(v0.z, v0.w);
    uu.z = pkbf(v1.x, v1.y);
    uu.w = pkbf(v1.z, v1.w);
    *(uint4*)&abuf[r][c8] = uu;
  }
  // stage sub -> abuf[:,128:192]
#pragma unroll
  for (int t = 0; t < 2; ++t) {
    int u = tid + t * 256;
    int r = u >> 3, c8 = (u & 7) * 8;
    const float* sp = &sub[(size_t)(row0 + r) * SS + c8];
    float4 v0 = *(const float4*)sp, v1 = *(const float4*)(sp + 4);
    uint4 uu;
    uu.x = pkbf(v0.x, v0.y);
    uu.y = pkbf(v0.z, v0.w);
    uu.z = pkbf(v1.x, v1.y);
    uu.w = pkbf(v1.z, v1.w);
    *(uint4*)&abuf[r][128 + c8] = uu;
  }
  if (tid < 64) bt[tid] = batch[row0 + tid];
  stage8k(w1t, &wstage[0][0], tid);
  stage8k(w1t + 4096, &wstage[1][0], tid);
  __syncthreads();

  int lane = tid & 63, wave = tid >> 6;
  int m16 = lane & 15, quad = lane >> 4;
  int mts = 4 * (wave >> 1), nts = 2 * (wave & 1);
  f32x4 acc[4][2];

  // ---- Phase A: se^T = W1^T @ sub^T ----
#pragma unroll
  for (int mi = 0; mi < 4; ++mi)
#pragma unroll
    for (int ni = 0; ni < 2; ++ni) acc[mi][ni] = (f32x4){0.f, 0.f, 0.f, 0.f};
  mfma8t(&wstage[0][0], &abuf[0][0], 128, m16, quad, mts, nts, acc);
  mfma8t(&wstage[1][0], &abuf[0][0], 160, m16, quad, mts, nts, acc);
  __syncthreads();  // sub reads complete
  stage8k(wgt, &wstage[0][0], tid);
#pragma unroll
  for (int mi = 0; mi < 4; ++mi) {
    int ch0 = (mts + mi) * 16 + quad * 4;
    float4 b1v = *(const float4*)&b1[ch0];
    float4 s1v = *(const float4*)&sc1[ch0];
    float4 h1v = *(const float4*)&sh1[ch0];
#pragma unroll
    for (int ni = 0; ni < 2; ++ni) {
      int row = (nts + ni) * 16 + m16;
      float se0 = fmaxf(fmaf(acc[mi][ni][0] + b1v.x, s1v.x, h1v.x), 0.f);
      float se1 = fmaxf(fmaf(acc[mi][ni][1] + b1v.y, s1v.y, h1v.y), 0.f);
      float se2 = fmaxf(fmaf(acc[mi][ni][2] + b1v.z, s1v.z, h1v.z), 0.f);
      float se3 = fmaxf(fmaf(acc[mi][ni][3] + b1v.w, s1v.w, h1v.w), 0.f);
      uint2 uu;
      uu.x = pkbf(se0, se1);
      uu.y = pkbf(se2, se3);
      *(uint2*)&abuf[row][128 + ch0] = uu;
    }
  }
  __syncthreads();  // se visible; wgt chunk0 staged

  // ---- Phase B: gate^T = Wg^T @ [h|se]^T ----
#pragma unroll
  for (int mi = 0; mi < 4; ++mi)
#pragma unroll
    for (int ni = 0; ni < 2; ++ni) acc[mi][ni] = (f32x4){0.f, 0.f, 0.f, 0.f};
#pragma unroll 1
  for (int c = 0; c < 8; ++c) {
    if (c < 7) stage8k(wgt + (size_t)(c + 1) * 4096, &wstage[(c + 1) & 1][0], tid);
    mfma8t(&wstage[c & 1][0], &abuf[0][0], c * 32, m16, quad, mts, nts, acc);
    __syncthreads();
  }
  stage8k(ws1t, &wstage[0][0], tid);
  // epilogue B: owner-computes (same lane owns se cell read and hd cell write)
#pragma unroll
  for (int mi = 0; mi < 4; ++mi) {
    int ch0 = (mts + mi) * 16 + quad * 4;
    float4 bgv = *(const float4*)&bg[ch0];
#pragma unroll
    for (int ni = 0; ni < 2; ++ni) {
      int row = (nts + ni) * 16 + m16;
      int grow = row0 + row;
      float4 hv = *(const float4*)&h[(size_t)grow * DD + ch0];
      uint2 seu = *(const uint2*)&abuf[row][128 + ch0];
      int g = bt[row];
      float4 gm = *(const float4*)&gmean[(size_t)g * DD + ch0];
      float4 gr = *(const float4*)&grstd[(size_t)g * DD + ch0];
      float g0 = fsig(acc[mi][ni][0] + bgv.x);
      float g1v = fsig(acc[mi][ni][1] + bgv.y);
      float g2 = fsig(acc[mi][ni][2] + bgv.z);
      float g3 = fsig(acc[mi][ni][3] + bgv.w);
      float hf0 = fmaf(g0, bf2f((unsigned short)(seu.x & 0xffff)), hv.x);
      float hf1 = fmaf(g1v, bf2f((unsigned short)(seu.x >> 16)), hv.y);
      float hf2 = fmaf(g2, bf2f((unsigned short)(seu.y & 0xffff)), hv.z);
      float hf3 = fmaf(g3, bf2f((unsigned short)(seu.y >> 16)), hv.w);
      float hd0 = (hv.x - gm.x) * gr.x;
      float hd1 = (hv.y - gm.y) * gr.y;
      float hd2 = (hv.z - gm.z) * gr.z;
      float hd3 = (hv.w - gm.w) * gr.w;
      float4 hfv = {hf0, hf1, hf2, hf3};
      *(float4*)&hfused[(size_t)grow * DD + ch0] = hfv;
      uint2 uf, ud;
      uf.x = pkbf(hf0, hf1);
      uf.y = pkbf(hf2, hf3);
      ud.x = pkbf(hd0, hd1);
      ud.y = pkbf(hd2, hd3);
      *(uint2*)&abuf[row][ch0] = uf;
      *(uint2*)&abuf[row][128 + ch0] = ud;
    }
  }
  __syncthreads();  // hf/hd visible; ws1 chunk0 staged

  // ---- Phase C: z^T = Ws1^T @ [hf|hd]^T ----
#pragma unroll
  for (int mi = 0; mi < 4; ++mi)
#pragma unroll
    for (int ni = 0; ni < 2; ++ni) acc[mi][ni] = (f32x4){0.f, 0.f, 0.f, 0.f};
#pragma unroll 1
  for (int c = 0; c < 8; ++c) {
    if (c < 7) stage8k(ws1t + (size_t)(c + 1) * 4096, &wstage[(c + 1) & 1][0], tid);
    mfma8t(&wstage[c & 1][0], &abuf[0][0], c * 32, m16, quad, mts, nts, acc);
    __syncthreads();
  }
  // epilogue C: bf16 zpre stores + bn2 partial sums via scratch in dead abuf
  float* scr = (float*)&abuf[0][0];   // s: [32][132] ; q at +4224
  int srow = (wave & 1) * 16 + m16;   // 32 row-slots (nts-half x m16)
#pragma unroll
  for (int mi = 0; mi < 4; ++mi) {
    int ch0 = (mts + mi) * 16 + quad * 4;
    float4 bsv = *(const float4*)&bs1[ch0];
    f32x4 s4 = (f32x4){0.f, 0.f, 0.f, 0.f};
    f32x4 q4 = (f32x4){0.f, 0.f, 0.f, 0.f};
#pragma unroll
    for (int ni = 0; ni < 2; ++ni) {
      int grow = row0 + (nts + ni) * 16 + m16;
      float z0 = acc[mi][ni][0] + bsv.x;
      float z1 = acc[mi][ni][1] + bsv.y;
      float z2 = acc[mi][ni][2] + bsv.z;
      float z3 = acc[mi][ni][3] + bsv.w;
      uint2 uz;
      uz.x = pkbf(z0, z1);
      uz.y = pkbf(z2, z3);
      *(uint2*)&zp16[(size_t)grow * DD + ch0] = uz;
      s4[0] += z0; s4[1] += z1; s4[2] += z2; s4[3] += z3;
      q4[0] = fmaf(z0, z0, q4[0]); q4[1] = fmaf(z1, z1, q4[1]);
      q4[2] = fmaf(z2, z2, q4[2]); q4[3] = fmaf(z3, z3, q4[3]);
    }
    *(f32x4*)&scr[srow * 132 + ch0] = s4;
    *(f32x4*)&scr[4224 + srow * 132 + ch0] = q4;
  }
  __syncthreads();
  if (tid < 128) {
    float s = 0.f, q = 0.f;
#pragma unroll 4
    for (int i = 0; i < 32; ++i) {
      s += scr[i * 132 + tid];
      q += scr[4224 + i * 132 + tid];
    }
    float* rp = &bn2p[(size_t)(blockIdx.x & (NREP - 1)) * 256];
    atomicAdd(&rp[tid], s);
    atomicAdd(&rp[128 + tid], q);
  }
}

// ---------- K56: logit -> e=exp(logit) -> accumulate denom & sum(hf*e) ------
// 4-deep pipelined row loop per 32-lane stripe.
__global__ __launch_bounds__(256, 6) void k56_score(
    const unsigned short* __restrict__ zp16, const float* __restrict__ hf,
    const int* __restrict__ batch, const float* __restrict__ sc2,
    const float* __restrict__ sh2, const float* __restrict__ Ws2,
    const float* __restrict__ bs2, float* __restrict__ denom,
    float* __restrict__ wf, int N) {
  __shared__ int bc[256];
  int tid = threadIdx.x;
  int row0 = blockIdx.x * 256;
  {
    int row = row0 + tid;
    bc[tid] = (row < N) ? batch[row] : -1;
  }
  __syncthreads();
  int stripe = tid >> 5, c4 = (tid & 31) * 4;
  float4 s2 = *(const float4*)&sc2[c4];
  float4 h2 = *(const float4*)&sh2[c4];
  float4 w2 = *(const float4*)&Ws2[c4];
  float b2 = bs2[0];
  float ax = 0, ay = 0, az = 0, aw = 0, ds = 0;
  int gcur = -1;
  uint2 vz[4];
  float4 vh[4];
  bool vval[4];
#pragma unroll
  for (int j = 0; j < 4; ++j) {
    int r = stripe + 8 * j;
    vval[j] = bc[r] >= 0;
    if (vval[j]) {
      vz[j] = *(const uint2*)&zp16[(size_t)(row0 + r) * DD + c4];
      vh[j] = *(const float4*)&hf[(size_t)(row0 + r) * DD + c4];
    }
  }
#pragma unroll 1
  for (int mit = 0; mit < 8; ++mit) {
#pragma unroll
    for (int j = 0; j < 4; ++j) {
      int it = mit * 4 + j;
      int r = stripe + 8 * it;
      bool valid = vval[j];
      uint2 z2v = vz[j];
      float4 hv = vh[j];
      bool nv = (it + 4 < 32) && (bc[r + 32] >= 0);
      vval[j] = nv;
      if (nv) {
        vz[j] = *(const uint2*)&zp16[(size_t)(row0 + r + 32) * DD + c4];
        vh[j] = *(const float4*)&hf[(size_t)(row0 + r + 32) * DD + c4];
      }
      if (valid) {
        int g = bc[r];
        if (g != gcur) {
          if (gcur >= 0) {
            float* wp = &wf[(size_t)gcur * DD + c4];
            atomicAdd(wp + 0, ax); atomicAdd(wp + 1, ay);
            atomicAdd(wp + 2, az); atomicAdd(wp + 3, aw);
            if ((tid & 31) == 0) atomicAdd(&denom[gcur], ds);
          }
          gcur = g;
          ax = ay = az = aw = ds = 0.f;
        }
        float z0 = bf2f((unsigned short)(z2v.x & 0xffff));
        float z1 = bf2f((unsigned short)(z2v.x >> 16));
        float zz2 = bf2f((unsigned short)(z2v.y & 0xffff));
        float z3 = bf2f((unsigned short)(z2v.y >> 16));
        float p = fmaxf(fmaf(z0, s2.x, h2.x), 0.f) * w2.x;
        p = fmaf(fmaxf(fmaf(z1, s2.y, h2.y), 0.f), w2.y, p);
        p = fmaf(fmaxf(fmaf(zz2, s2.z, h2.z), 0.f), w2.z, p);
        p = fmaf(fmaxf(fmaf(z3, s2.w, h2.w), 0.f), w2.w, p);
        p += __shfl_xor(p, 16); p += __shfl_xor(p, 8);
        p += __shfl_xor(p, 4);  p += __shfl_xor(p, 2);
        p += __shfl_xor(p, 1);
        float e = __expf(p + b2);
        ax = fmaf(hv.x, e, ax); ay = fmaf(hv.y, e, ay);
        az = fmaf(hv.z, e, az); aw = fmaf(hv.w, e, aw);
        ds += e;
      }
    }
  }
  if (gcur >= 0) {
    float* wp = &wf[(size_t)gcur * DD + c4];
    atomicAdd(wp + 0, ax); atomicAdd(wp + 1, ay);
    atomicAdd(wp + 2, az); atomicAdd(wp + 3, aw);
    if ((tid & 31) == 0) atomicAdd(&denom[gcur], ds);
  }
}

// ---------- K7: out = alpha*wf/denom + (1-alpha)*gmean ----------
__global__ void k7_out(const float* __restrict__ wf, const float* __restrict__ denom,
                       const float* __restrict__ gmean, const float* __restrict__ mix,
                       float* __restrict__ out) {
  int g = blockIdx.x, d = threadIdx.x;
  float alpha = 1.f / (1.f + expf(-mix[0]));
  float dn = denom[g];
  size_t idx = (size_t)g * DD + d;
  float w = (dn > 0.f) ? wf[idx] / dn : 0.f;
  out[idx] = alpha * w + (1.f - alpha) * gmean[idx];
}

extern "C" void kernel_launch(void* const* d_in, const int* in_sizes, int n_in,
                              void* d_out, int out_size, void* d_ws, size_t ws_size,
                              hipStream_t stream) {
  const float* h   = (const float*)d_in[0];
  const float* sub = (const float*)d_in[1];
  const int* batch = (const int*)d_in[2];
  const float* W1  = (const float*)d_in[3];
  const float* b1  = (const float*)d_in[4];
  const float* g1  = (const float*)d_in[5];
  const float* be1 = (const float*)d_in[6];
  const float* Wg  = (const float*)d_in[7];
  const float* bg  = (const float*)d_in[8];
  const float* Ws1 = (const float*)d_in[9];
  const float* bs1 = (const float*)d_in[10];
  const float* g2  = (const float*)d_in[11];
  const float* be2 = (const float*)d_in[12];
  const float* Ws2 = (const float*)d_in[13];
  const float* bs2 = (const float*)d_in[14];
  const float* mix = (const float*)d_in[15];
  float* out = (float*)d_out;
  const int N = in_sizes[0] / DD;  // 400000 (divisible by 64)
  const int nB1 = N / 64;          // 6250
  const int nBG = (N + 255) / 256; // 1563

  float* ws = (float*)d_ws;
  size_t off = 0;
  float* hf    = ws + off; off += (size_t)N * DD;
  unsigned short* zp16 = (unsigned short*)(ws + off); off += (size_t)N * DD / 2;
  float* zbase = ws + off;
  float* gsum  = ws + off; off += (size_t)GG * DD;
  float* gsq   = ws + off; off += (size_t)GG * DD;
  float* wf    = ws + off; off += (size_t)GG * DD;
  float* bn1p  = ws + off; off += (size_t)NREP * 256;
  float* bn2p  = ws + off; off += (size_t)NREP * 256;
  float* counts = ws + off; off += GG;
  float* denom  = ws + off; off += GG;
  size_t zcount = (size_t)(ws + off - zbase);
  float* gmean = ws + off; off += (size_t)GG * DD;
  float* grstd = ws + off; off += (size_t)GG * DD;
  float* sc1 = ws + off; off += 128;
  float* sh1 = ws + off; off += 128;
  float* sc2 = ws + off; off += 128;
  float* sh2 = ws + off; off += 128;
  // weight images: sizes in SHORTS; offsets advance in FLOAT units (shorts/2).
  unsigned short* w1t  = (unsigned short*)(ws + off); off += 8192 / 2;    // 2 chunks x 4096 shorts
  unsigned short* wgt  = (unsigned short*)(ws + off); off += 32768 / 2;   // 8 chunks x 4096 shorts
  unsigned short* ws1t = (unsigned short*)(ws + off); off += 32768 / 2;   // 8 chunks x 4096 shorts

  hipMemsetAsync(zbase, 0, zcount * sizeof(float), stream);
  w_prep<<<18, 256, 0, stream>>>(W1, Wg, Ws1, w1t, wgt, ws1t);

  k1_fused<<<nB1 + nBG, 256, 0, stream>>>(sub, w1t, b1, bn1p,
                                          h, batch, gsum, gsq, counts, N, nBG);
  k2_fused<<<1 + GG, 128, 0, stream>>>(bn1p, g1, be1, sc1, sh1, (float)N,
                                       gsum, gsq, counts, gmean, grstd);

  k3_main<<<nB1, 256, 0, stream>>>(h, sub, batch, w1t, wgt, ws1t, b1, sc1, sh1,
                                   bg, bs1, gmean, grstd, hf, zp16, bn2p, N);

  k2a_bn_final<<<1, 128, 0, stream>>>(bn2p, g2, be2, sc2, sh2, (float)N);
  k56_score<<<nBG, 256, 0, stream>>>(zp16, hf, batch, sc2, sh2, Ws2, bs2,
                                     denom, wf, N);
  k7_out<<<GG, 128, 0, stream>>>(wf, denom, gmean, mix, out);
}